// Round 1
// baseline (653.642 us; speedup 1.0000x reference)
//
#include <hip/hip_runtime.h>
#include <math.h>

#define D 1024
#define NROW 128
#define PANEL 16
#define NPANELS 8
#define NTHREADS 1024

// OUT[j][p] = (sum_d A[j][d]*B[p][d]) * (rscale ? rscale[j] : 1)
// 16 waves: one 4x4 (j,p) tile per wave, 64-way d-split, butterfly reduce.
__device__ __forceinline__ void dots16x16(const float (*__restrict__ A)[D],
                                          const float (*__restrict__ B)[D],
                                          float (*__restrict__ OUT)[PANEL],
                                          const float* __restrict__ rscale,
                                          int t) {
  const int lane = t & 63;
  const int tile = t >> 6;            // 0..15, one tile per wave
  const int j0 = (tile & 3) << 2;
  const int p0 = (tile >> 2) << 2;
  float acc[4][4];
#pragma unroll
  for (int a = 0; a < 4; ++a)
#pragma unroll
    for (int b = 0; b < 4; ++b) acc[a][b] = 0.0f;

#pragma unroll
  for (int s = 0; s < 4; ++s) {
    const int base = s * 256 + lane * 4;   // lanes cover 256 consecutive floats
    float4 av[4], bv[4];
#pragma unroll
    for (int a = 0; a < 4; ++a) av[a] = *(const float4*)&A[j0 + a][base];
#pragma unroll
    for (int b = 0; b < 4; ++b) bv[b] = *(const float4*)&B[p0 + b][base];
#pragma unroll
    for (int a = 0; a < 4; ++a)
#pragma unroll
      for (int b = 0; b < 4; ++b)
        acc[a][b] += av[a].x * bv[b].x + av[a].y * bv[b].y +
                     av[a].z * bv[b].z + av[a].w * bv[b].w;
  }
#pragma unroll
  for (int mask = 32; mask >= 1; mask >>= 1) {
#pragma unroll
    for (int a = 0; a < 4; ++a)
#pragma unroll
      for (int b = 0; b < 4; ++b)
        acc[a][b] += __shfl_xor(acc[a][b], mask);
  }
  if (lane == 0) {
#pragma unroll
    for (int a = 0; a < 4; ++a) {
      const float sc = rscale ? rscale[j0 + a] : 1.0f;
      float4 o;
      o.x = acc[a][0] * sc; o.y = acc[a][1] * sc;
      o.z = acc[a][2] * sc; o.w = acc[a][3] * sc;
      *(float4*)&OUT[j0 + a][p0] = o;
    }
  }
}

__global__ __launch_bounds__(NTHREADS) void gs_kernel(const float* __restrict__ xg_all,
                                                      float* __restrict__ qg_all) {
  __shared__ float Xc[PANEL][D];        // 64 KB: current panel (corrected in place)
  __shared__ float Qch[PANEL][D];       // 64 KB: staged previous-Q chunk / output panel
  __shared__ float Sm[PANEL][PANEL];    // scaled dots (cross-panel)
  __shared__ float Gm[PANEL][PANEL];    // within-panel Gram matrix
  __shared__ float LT[PANEL][PANEL];    // LT[r][m] = L[m][r]
  __shared__ float rinv[NROW];          // reciprocals of ||q_j||^2

  const int t = threadIdx.x;
  const size_t off = (size_t)blockIdx.x * (size_t)NROW * D;
  const float* xg = xg_all + off;
  float* qg = qg_all + off;

  float csum = 0.0f;                    // column-sum-of-squares for column d = t

  for (int k = 0; k < NPANELS; ++k) {
    const int i0 = k * PANEL;

    { // ---- load panel rows [i0, i0+16) into Xc ----
      const float4* src = (const float4*)(xg + (size_t)i0 * D);
      float4* dst = (float4*)&Xc[0][0];
#pragma unroll
      for (int r = 0; r < 4; ++r) dst[r * NTHREADS + t] = src[r * NTHREADS + t];
    }
    __syncthreads();

    // ---- cross-panel corrections: subtract projections onto finalized Q ----
    for (int c = 0; c < k; ++c) {
      { // stage Q chunk rows [16c, 16c+16)
        const float4* src = (const float4*)(qg + (size_t)c * PANEL * D);
        float4* dst = (float4*)&Qch[0][0];
#pragma unroll
        for (int r = 0; r < 4; ++r) dst[r * NTHREADS + t] = src[r * NTHREADS + t];
      }
      __syncthreads();

      // Sm[j][p] = (q_j . x_p) / ||q_j||^2
      dots16x16(Qch, Xc, Sm, &rinv[c * PANEL], t);
      __syncthreads();

      { // Xc[p][d] -= sum_j Sm[j][p] * Qch[j][d]   (4 p's x 4 d's per thread)
        const int p0 = (t >> 8) << 2;
        const int d0 = (t & 255) << 2;
        float4 xc0 = *(const float4*)&Xc[p0 + 0][d0];
        float4 xc1 = *(const float4*)&Xc[p0 + 1][d0];
        float4 xc2 = *(const float4*)&Xc[p0 + 2][d0];
        float4 xc3 = *(const float4*)&Xc[p0 + 3][d0];
#pragma unroll
        for (int j = 0; j < PANEL; ++j) {
          const float4 q = *(const float4*)&Qch[j][d0];
          const float4 s = *(const float4*)&Sm[j][p0];   // wave-uniform broadcast
          xc0.x -= s.x * q.x; xc0.y -= s.x * q.y; xc0.z -= s.x * q.z; xc0.w -= s.x * q.w;
          xc1.x -= s.y * q.x; xc1.y -= s.y * q.y; xc1.z -= s.y * q.z; xc1.w -= s.y * q.w;
          xc2.x -= s.z * q.x; xc2.y -= s.z * q.y; xc2.z -= s.z * q.z; xc2.w -= s.z * q.w;
          xc3.x -= s.w * q.x; xc3.y -= s.w * q.y; xc3.z -= s.w * q.z; xc3.w -= s.w * q.w;
        }
        *(float4*)&Xc[p0 + 0][d0] = xc0;
        *(float4*)&Xc[p0 + 1][d0] = xc1;
        *(float4*)&Xc[p0 + 2][d0] = xc2;
        *(float4*)&Xc[p0 + 3][d0] = xc3;
      }
      __syncthreads();
    }

    // ---- within-panel: Gram matrix, then 16x16 solve in Gram domain ----
    dots16x16(Xc, Xc, Gm, nullptr, t);
    __syncthreads();

    if (t < 64) {  // single-wave triangular solve: Q_panel = L * X_panel
      const int r = t & 15;
      float Lreg[PANEL];   // lane r holds L[m][r]
      float rn[PANEL];
#pragma unroll
      for (int m = 0; m < PANEL; ++m) {
        const float g = Gm[r][m];
        float accL = (r == m) ? 1.0f : 0.0f;
        float nm = Gm[m][m];
#pragma unroll
        for (int j = 0; j < m; ++j) {
          float p = Lreg[j] * g;               // partial of d_jm = q_j . x_m
          p += __shfl_xor(p, 1);
          p += __shfl_xor(p, 2);
          p += __shfl_xor(p, 4);
          p += __shfl_xor(p, 8);               // 16-lane reduce; all lanes get d_jm
          const float cj = p * rn[j];
          accL -= cj * Lreg[j];
          nm -= cj * p;                         // n_m = G_mm - sum d^2/n
        }
        Lreg[m] = accL;
        rn[m] = 1.0f / nm;
        if (t == 0) rinv[i0 + m] = rn[m];
      }
      if (t < 16) {
#pragma unroll
        for (int m = 0; m < PANEL; ++m) LT[r][m] = Lreg[m];
      }
    }
    __syncthreads();

    { // ---- GEMM3: Qch[m][d] = sum_r LT[r][m] * Xc[r][d] ----
      const int m0 = (t >> 8) << 2;
      const int d0 = (t & 255) << 2;
      float4 a0 = {0.f,0.f,0.f,0.f}, a1 = {0.f,0.f,0.f,0.f};
      float4 a2 = {0.f,0.f,0.f,0.f}, a3 = {0.f,0.f,0.f,0.f};
#pragma unroll
      for (int r = 0; r < PANEL; ++r) {
        const float4 xv = *(const float4*)&Xc[r][d0];
        const float4 lt = *(const float4*)&LT[r][m0];    // wave-uniform broadcast
        a0.x += lt.x * xv.x; a0.y += lt.x * xv.y; a0.z += lt.x * xv.z; a0.w += lt.x * xv.w;
        a1.x += lt.y * xv.x; a1.y += lt.y * xv.y; a1.z += lt.y * xv.z; a1.w += lt.y * xv.w;
        a2.x += lt.z * xv.x; a2.y += lt.z * xv.y; a2.z += lt.z * xv.z; a2.w += lt.z * xv.w;
        a3.x += lt.w * xv.x; a3.y += lt.w * xv.y; a3.z += lt.w * xv.z; a3.w += lt.w * xv.w;
      }
      *(float4*)&Qch[m0 + 0][d0] = a0;
      *(float4*)&Qch[m0 + 1][d0] = a1;
      *(float4*)&Qch[m0 + 2][d0] = a2;
      *(float4*)&Qch[m0 + 3][d0] = a3;
    }
    __syncthreads();

    // ---- accumulate column sums (for final normalization) + store panel ----
#pragma unroll
    for (int m = 0; m < PANEL; ++m) {
      const float v = Qch[m][t];
      csum += v * v;
    }
    {
      const float4* src = (const float4*)&Qch[0][0];
      float4* dst = (float4*)(qg + (size_t)i0 * D);
#pragma unroll
      for (int r = 0; r < 4; ++r) dst[r * NTHREADS + t] = src[r * NTHREADS + t];
    }
    __syncthreads();
  }

  // ---- final column-wise normalization: out[i][d] /= ||column d|| ----
  const float inv = 1.0f / sqrtf(csum);
  for (int i = 0; i < NROW; ++i) {
    qg[(size_t)i * D + t] *= inv;
  }
}

extern "C" void kernel_launch(void* const* d_in, const int* in_sizes, int n_in,
                              void* d_out, int out_size, void* d_ws, size_t ws_size,
                              hipStream_t stream) {
  const float* x = (const float*)d_in[0];
  float* out = (float*)d_out;
  // 256 (b,c) matrices -> 256 blocks (one per CU), 1024 threads each.
  gs_kernel<<<dim3(256), dim3(NTHREADS), 0, stream>>>(x, out);
}

// Round 2
// 621.337 us; speedup vs baseline: 1.0520x; 1.0520x over previous
//
#include <hip/hip_runtime.h>
#include <math.h>

#define D 1024
#define NROW 128
#define PANEL 16
#define NPANELS 8
#define NTHREADS 1024
#define XP 1028   // Xc row pitch in floats: +16B rotates banks per row -> uniform b128 frag reads
#define QP 1032   // Qb row pitch in bf16:  +16B ditto

typedef __attribute__((ext_vector_type(8))) short short8;
typedef __attribute__((ext_vector_type(4))) float floatx4;

__device__ __forceinline__ unsigned short f2bf(float f) {  // RNE f32 -> bf16 (inputs are finite)
  unsigned int u = __builtin_bit_cast(unsigned int, f);
  u += 0x7fffu + ((u >> 16) & 1u);
  return (unsigned short)(u >> 16);
}
__device__ __forceinline__ float bf2f(unsigned short s) {
  return __builtin_bit_cast(float, ((unsigned int)s) << 16);
}

__global__ __launch_bounds__(NTHREADS) void gs_kernel(const float* __restrict__ xg_all,
                                                      float* __restrict__ qg_all) {
  __shared__ __align__(16) float Xc[PANEL][XP];          // ~64 KB fp32 master panel
  __shared__ __align__(16) unsigned short Qb[PANEL][QP]; // ~32 KB bf16 staged Q chunk
  __shared__ __align__(16) float Scr[4096];              // 16 KB: MFMA partials / csum partials / colinv
  __shared__ float Sm[PANEL][PANEL];
  __shared__ float Gm[PANEL][PANEL];
  __shared__ float LT[PANEL][PANEL];                     // LT[r][m] = L[m][r]
  __shared__ float rinv[NROW];

  const int t = threadIdx.x;
  const int lane = t & 63;
  const int w = t >> 6;
  const size_t off = (size_t)blockIdx.x * (NROW * D);
  const float* xg = xg_all + off;
  float* qg = qg_all + off;

  float csum = 0.0f;   // column t sum of squares
  float4 xr[4], qr[4]; // register prefetch buffers (X panel / Q chunk)

  { // prefetch panel 0
    const float4* s = (const float4*)xg;
#pragma unroll
    for (int r = 0; r < 4; ++r) xr[r] = s[r * 1024 + t];
  }

  for (int k = 0; k < NPANELS; ++k) {
    const int i0 = k * PANEL;

    // ---- commit prefetched X panel to LDS ----
#pragma unroll
    for (int r = 0; r < 4; ++r) {
      const int idx = r * 1024 + t;
      *(float4*)&Xc[idx >> 8][(idx & 255) << 2] = xr[r];
    }
    if (k + 1 < NPANELS) { // prefetch next X panel (consumed next iteration)
      const float4* s = (const float4*)(xg + (size_t)(k + 1) * (PANEL * D));
#pragma unroll
      for (int r = 0; r < 4; ++r) xr[r] = s[r * 1024 + t];
    }
    __syncthreads();

    // ---- cross-panel corrections ----
    for (int c = 0; c < k; ++c) {
      // commit prefetched Q chunk (fp32 regs -> bf16 LDS)
#pragma unroll
      for (int r = 0; r < 4; ++r) {
        const int idx = r * 1024 + t;
        ushort4 u;
        u.x = f2bf(qr[r].x); u.y = f2bf(qr[r].y);
        u.z = f2bf(qr[r].z); u.w = f2bf(qr[r].w);
        *(ushort4*)&Qb[idx >> 8][(idx & 255) << 2] = u;
      }
      { // prefetch next chunk: (k, c+1), else (k+1, 0) (rows 0..15, written at panel 0, k>=1 here)
        const float4* s = nullptr;
        if (c + 1 < k) s = (const float4*)(qg + (size_t)(c + 1) * (PANEL * D));
        else if (k + 1 < NPANELS) s = (const float4*)qg;
        if (s) {
#pragma unroll
          for (int r = 0; r < 4; ++r) qr[r] = s[r * 1024 + t];
        }
      }
      __syncthreads();

      // ---- dots via MFMA: partial tiles, wave w covers K in [64w, 64w+64) ----
      {
        const int m = lane & 15;
        const int kb = lane >> 4;
        floatx4 acc = {0.f, 0.f, 0.f, 0.f};
#pragma unroll
        for (int h = 0; h < 2; ++h) {
          const int kk = w * 64 + kb * 8 + h * 32;
          short8 a = *(const short8*)&Qb[m][kk];          // A[j=m][k..k+7]
          const float4 xlo = *(const float4*)&Xc[m][kk];  // B row p=m, fp32 -> bf16
          const float4 xhi = *(const float4*)&Xc[m][kk + 4];
          short8 b;
          b[0] = (short)f2bf(xlo.x); b[1] = (short)f2bf(xlo.y);
          b[2] = (short)f2bf(xlo.z); b[3] = (short)f2bf(xlo.w);
          b[4] = (short)f2bf(xhi.x); b[5] = (short)f2bf(xhi.y);
          b[6] = (short)f2bf(xhi.z); b[7] = (short)f2bf(xhi.w);
          acc = __builtin_amdgcn_mfma_f32_16x16x32_bf16(a, b, acc, 0, 0, 0);
        }
#pragma unroll
        for (int r = 0; r < 4; ++r) Scr[w * 256 + r * 64 + lane] = acc[r];
      }
      __syncthreads();
      if (t < 256) { // reduce 16 partial tiles; C/D map: col=lane&15, row=(lane>>4)*4+reg
        float s = 0.f;
#pragma unroll
        for (int ww = 0; ww < 16; ++ww) s += Scr[ww * 256 + t];
        const int j = ((t & 63) >> 4) * 4 + (t >> 6);
        Sm[j][t & 15] = s * rinv[c * PANEL + j];
      }
      __syncthreads();

      // ---- update: Xc[p][d] -= sum_j Sm[j][p] * Qb[j][d] ----
      {
        const int p0 = (t >> 8) << 2;
        const int d0 = (t & 255) << 2;
        float4 x0 = *(const float4*)&Xc[p0 + 0][d0];
        float4 x1 = *(const float4*)&Xc[p0 + 1][d0];
        float4 x2 = *(const float4*)&Xc[p0 + 2][d0];
        float4 x3 = *(const float4*)&Xc[p0 + 3][d0];
#pragma unroll
        for (int j = 0; j < PANEL; ++j) {
          const ushort4 qu = *(const ushort4*)&Qb[j][d0];
          const float4 s = *(const float4*)&Sm[j][p0];    // wave-uniform broadcast
          const float q0 = bf2f(qu.x), q1 = bf2f(qu.y), q2 = bf2f(qu.z), q3 = bf2f(qu.w);
          x0.x -= s.x * q0; x0.y -= s.x * q1; x0.z -= s.x * q2; x0.w -= s.x * q3;
          x1.x -= s.y * q0; x1.y -= s.y * q1; x1.z -= s.y * q2; x1.w -= s.y * q3;
          x2.x -= s.z * q0; x2.y -= s.z * q1; x2.z -= s.z * q2; x2.w -= s.z * q3;
          x3.x -= s.w * q0; x3.y -= s.w * q1; x3.z -= s.w * q2; x3.w -= s.w * q3;
        }
        *(float4*)&Xc[p0 + 0][d0] = x0;
        *(float4*)&Xc[p0 + 1][d0] = x1;
        *(float4*)&Xc[p0 + 2][d0] = x2;
        *(float4*)&Xc[p0 + 3][d0] = x3;
      }
      __syncthreads();
    }

    // ---- within-panel Gram via MFMA (A = B = bf16(Xc)) ----
    {
      const int m = lane & 15;
      const int kb = lane >> 4;
      floatx4 acc = {0.f, 0.f, 0.f, 0.f};
#pragma unroll
      for (int h = 0; h < 2; ++h) {
        const int kk = w * 64 + kb * 8 + h * 32;
        const float4 xlo = *(const float4*)&Xc[m][kk];
        const float4 xhi = *(const float4*)&Xc[m][kk + 4];
        short8 a;
        a[0] = (short)f2bf(xlo.x); a[1] = (short)f2bf(xlo.y);
        a[2] = (short)f2bf(xlo.z); a[3] = (short)f2bf(xlo.w);
        a[4] = (short)f2bf(xhi.x); a[5] = (short)f2bf(xhi.y);
        a[6] = (short)f2bf(xhi.z); a[7] = (short)f2bf(xhi.w);
        acc = __builtin_amdgcn_mfma_f32_16x16x32_bf16(a, a, acc, 0, 0, 0);
      }
#pragma unroll
      for (int r = 0; r < 4; ++r) Scr[w * 256 + r * 64 + lane] = acc[r];
    }
    __syncthreads();
    if (t < 256) {
      float s = 0.f;
#pragma unroll
      for (int ww = 0; ww < 16; ++ww) s += Scr[ww * 256 + t];
      const int j = ((t & 63) >> 4) * 4 + (t >> 6);
      Gm[j][t & 15] = s;
    }
    __syncthreads();

    // ---- single-wave triangular solve in Gram domain (verbatim R1, verified) ----
    if (t < 64) {
      const int r = t & 15;
      float Lreg[PANEL];
      float rn[PANEL];
#pragma unroll
      for (int m = 0; m < PANEL; ++m) {
        const float g = Gm[r][m];
        float accL = (r == m) ? 1.0f : 0.0f;
        float nm = Gm[m][m];
#pragma unroll
        for (int j = 0; j < m; ++j) {
          float p = Lreg[j] * g;
          p += __shfl_xor(p, 1);
          p += __shfl_xor(p, 2);
          p += __shfl_xor(p, 4);
          p += __shfl_xor(p, 8);
          const float cj = p * rn[j];
          accL -= cj * Lreg[j];
          nm -= cj * p;
        }
        Lreg[m] = accL;
        rn[m] = 1.0f / nm;
        if (t == 0) rinv[i0 + m] = rn[m];
      }
      if (t < 16) {
#pragma unroll
        for (int m = 0; m < PANEL; ++m) LT[r][m] = Lreg[m];
      }
    }
    __syncthreads();

    // ---- gemm3: Q_panel = L * X_panel (fp32, exact diagonal) -> global + csum partials ----
    {
      const int m0 = (t >> 8) << 2;
      const int d0 = (t & 255) << 2;
      float4 a0 = {0.f,0.f,0.f,0.f}, a1 = {0.f,0.f,0.f,0.f};
      float4 a2 = {0.f,0.f,0.f,0.f}, a3 = {0.f,0.f,0.f,0.f};
#pragma unroll
      for (int r = 0; r < PANEL; ++r) {
        const float4 xv = *(const float4*)&Xc[r][d0];
        const float4 lt = *(const float4*)&LT[r][m0];     // wave-uniform broadcast
        a0.x += lt.x * xv.x; a0.y += lt.x * xv.y; a0.z += lt.x * xv.z; a0.w += lt.x * xv.w;
        a1.x += lt.y * xv.x; a1.y += lt.y * xv.y; a1.z += lt.y * xv.z; a1.w += lt.y * xv.w;
        a2.x += lt.z * xv.x; a2.y += lt.z * xv.y; a2.z += lt.z * xv.z; a2.w += lt.z * xv.w;
        a3.x += lt.w * xv.x; a3.y += lt.w * xv.y; a3.z += lt.w * xv.z; a3.w += lt.w * xv.w;
      }
      *(float4*)(qg + (size_t)(i0 + m0 + 0) * D + d0) = a0;
      *(float4*)(qg + (size_t)(i0 + m0 + 1) * D + d0) = a1;
      *(float4*)(qg + (size_t)(i0 + m0 + 2) * D + d0) = a2;
      *(float4*)(qg + (size_t)(i0 + m0 + 3) * D + d0) = a3;
      float4 ps;
      ps.x = a0.x*a0.x + a1.x*a1.x + a2.x*a2.x + a3.x*a3.x;
      ps.y = a0.y*a0.y + a1.y*a1.y + a2.y*a2.y + a3.y*a3.y;
      ps.z = a0.z*a0.z + a1.z*a1.z + a2.z*a2.z + a3.z*a3.z;
      ps.w = a0.w*a0.w + a1.w*a1.w + a2.w*a2.w + a3.w*a3.w;
      *(float4*)&Scr[(t >> 8) * 1024 + d0] = ps;
    }
    __syncthreads();  // also makes gemm3's global stores visible (vmcnt(0) before s_barrier)
    csum += Scr[t] + Scr[1024 + t] + Scr[2048 + t] + Scr[3072 + t];
    if (k == 0 && NPANELS > 1) { // prefetch chunk (1,0): panel-0 Q now visible
      const float4* s = (const float4*)qg;
#pragma unroll
      for (int r = 0; r < 4; ++r) qr[r] = s[r * 1024 + t];
    }
    __syncthreads();
  }

  // ---- final column-wise normalization, float4-vectorized ----
  Scr[t] = 1.0f / sqrtf(csum);
  __syncthreads();
  {
    float4* qv = (float4*)qg;
#pragma unroll 4
    for (int i = 0; i < 32; ++i) {
      const int f = i * 1024 + t;
      const float4 inv4 = *(const float4*)&Scr[(f & 255) << 2];
      float4 v = qv[f];
      v.x *= inv4.x; v.y *= inv4.y; v.z *= inv4.z; v.w *= inv4.w;
      qv[f] = v;
    }
  }
}

extern "C" void kernel_launch(void* const* d_in, const int* in_sizes, int n_in,
                              void* d_out, int out_size, void* d_ws, size_t ws_size,
                              hipStream_t stream) {
  const float* x = (const float*)d_in[0];
  float* out = (float*)d_out;
  gs_kernel<<<dim3(256), dim3(NTHREADS), 0, stream>>>(x, out);
}